// Round 3
// baseline (1847.512 us; speedup 1.0000x reference)
//
#include <hip/hip_runtime.h>
#include <hip/hip_bf16.h>
#include <hip/hip_fp16.h>
#include <cstdint>
#include <cstddef>

#define NN 100000
#define EE 1600000
#define GG 2048

#define NOCT 8
#define OCTW 12500                    // NN / NOCT rows per src-octant
#define SLICE_BYTES (OCTW * 256)      // 3,200,000 B: octant slice of H (fits 4 MB L2)
#define NBLK_AGG 1024                 // 4 blocks/CU co-resident (launch_bounds(256,4))
#define NGRP (NBLK_AGG * 16)          // 16384 16-lane groups
#define NSLOT 7                       // ceil(NN / NGRP)
#define PFCHUNK (SLICE_BYTES / 128)   // 25,000 B prefetch chunk per block (128 blocks/XCD)

constexpr int NB_CNT = (EE + NN + 255) / 256;   // 6641 count blocks
constexpr int NB_GEMM = NN / 16;                // 6250 gemm blocks

__device__ __forceinline__ float lrelu(float v) { return v > 0.f ? v : 0.2f * v; }

// ---------------- shared GEMM body (layer GEMM + attention-logit epilogue) --
// One wave = 4 rows; x-row pointers wave-uniform (SGPR via readfirstlane).
template <int FIN>
__device__ __forceinline__ void gemm_body(int bidx, const float* __restrict__ X,
                                          const float* __restrict__ W,
                                          const float* __restrict__ asrc,
                                          const float* __restrict__ adst,
                                          float* __restrict__ H,
                                          float* __restrict__ als,
                                          float* __restrict__ ald) {
    int j  = threadIdx.x & 63;
    int ty = threadIdx.x >> 6;
    int row = __builtin_amdgcn_readfirstlane(bidx * 16 + ty * 4);
    const float* x0 = X + (size_t)row * FIN;
    const float* x1 = x0 + FIN;
    const float* x2 = x1 + FIN;
    const float* x3 = x2 + FIN;
    float a0 = 0.f, a1 = 0.f, a2 = 0.f, a3 = 0.f;
#pragma unroll
    for (int k = 0; k < FIN; k += 4) {
        float4 xa = *(const float4*)(x0 + k);
        float4 xb = *(const float4*)(x1 + k);
        float4 xc = *(const float4*)(x2 + k);
        float4 xd = *(const float4*)(x3 + k);
        float w0 = W[(k + 0) * 64 + j];
        float w1 = W[(k + 1) * 64 + j];
        float w2 = W[(k + 2) * 64 + j];
        float w3 = W[(k + 3) * 64 + j];
        a0 += xa.x * w0 + xa.y * w1 + xa.z * w2 + xa.w * w3;
        a1 += xb.x * w0 + xb.y * w1 + xb.z * w2 + xb.w * w3;
        a2 += xc.x * w0 + xc.y * w1 + xc.z * w2 + xc.w * w3;
        a3 += xd.x * w0 + xd.y * w1 + xd.z * w2 + xd.w * w3;
    }
    H[(size_t)(row + 0) * 64 + j] = a0;
    H[(size_t)(row + 1) * 64 + j] = a1;
    H[(size_t)(row + 2) * 64 + j] = a2;
    H[(size_t)(row + 3) * 64 + j] = a3;
    float asj = asrc[j], adj = adst[j];
    float accs[4] = {a0, a1, a2, a3};
#pragma unroll
    for (int r = 0; r < 4; r++) {
        float vs = accs[r] * asj;
        float vd = accs[r] * adj;
#pragma unroll
        for (int off = 8; off > 0; off >>= 1) {
            vs += __shfl_xor(vs, off, 64);
            vd += __shfl_xor(vd, off, 64);
        }
        if ((j & 15) == 0) {
            int h = j >> 4;
            als[(size_t)(row + r) * 4 + h] = vs;
            ald[(size_t)(row + r) * 4 + h] = vd;
        }
    }
}

template <int FIN>
__global__ __launch_bounds__(256) void k_gemm(const float* __restrict__ X,
                                              const float* __restrict__ W,
                                              const float* __restrict__ asrc,
                                              const float* __restrict__ adst,
                                              float* __restrict__ H,
                                              float* __restrict__ als,
                                              float* __restrict__ ald) {
    gemm_body<FIN>(blockIdx.x, X, W, asrc, adst, H, als, ald);
}

// ---------------- fused (dst,src-octant) histogram + layer-0 GEMM -----------
// The two are independent; counting is atomic-latency-bound, the GEMM is
// VALU/stream-bound -> overlapping them in one grid hides the cheaper one.
__global__ __launch_bounds__(256) void k_cg(const int* __restrict__ ei,
                                            int* __restrict__ deg2,
                                            int* __restrict__ rank2,
                                            const float* __restrict__ X,
                                            const float* __restrict__ W,
                                            const float* __restrict__ asrc,
                                            const float* __restrict__ adst,
                                            float* __restrict__ H,
                                            float* __restrict__ als,
                                            float* __restrict__ ald) {
    if (blockIdx.x < NB_CNT) {
        int i = blockIdx.x * 256 + threadIdx.x;
        if (i < EE + NN) {
            int s, d;
            if (i < EE) { s = ei[i]; d = ei[EE + i]; } else { s = d = i - EE; }
            unsigned oct = (unsigned)s / OCTW;
            rank2[i] = atomicAdd(&deg2[d * 8 + oct], 1);
        }
    } else {
        gemm_body<128>(blockIdx.x - NB_CNT, X, W, asrc, adst, H, als, ald);
    }
}

// ---------------- per-(dst,octant) segment offsets (unordered alloc) --------
__global__ void k_alloc2(const int* __restrict__ deg2, int* __restrict__ starts,
                         int* __restrict__ cursor, const float* __restrict__ head_b,
                         float* __restrict__ out) {
    int i = blockIdx.x * 256 + threadIdx.x;
    int lane = threadIdx.x & 63;
    int rel[8];
    int tot = 0;
    if (i < NN) {
#pragma unroll
        for (int o = 0; o < 8; o++) { rel[o] = tot; tot += deg2[i * 8 + o]; }
    }
    int incl = tot;
#pragma unroll
    for (int off = 1; off < 64; off <<= 1) {
        int t = __shfl_up(incl, off, 64);
        if (lane >= off) incl += t;
    }
    int wtot = __shfl(incl, 63, 64);
    int base = 0;
    if (lane == 63) base = atomicAdd(cursor, wtot);
    base = __shfl(base, 63, 64);
    int mybase = base + incl - tot;
    if (i < NN) {
#pragma unroll
        for (int o = 0; o < 8; o++) starts[i * 8 + o] = mybase + rel[o];
    }
    if (i < GG) out[i] = head_b[0];
}

__global__ void k_scatter2(const int* __restrict__ ei, const int* __restrict__ starts,
                           const int* __restrict__ rank2, int* __restrict__ col) {
    int i = blockIdx.x * blockDim.x + threadIdx.x;
    if (i >= EE + NN) return;
    int s, d;
    if (i < EE) { s = ei[i]; d = ei[EE + i]; } else { s = d = i - EE; }
    unsigned oct = (unsigned)s / OCTW;
    col[starts[d * 8 + oct] + rank2[i]] = s;
}

// ---------------- octant-phased gather ---------------------------------------
// 1024 blocks, 4/CU co-resident; register accumulators for up to 7 nodes per
// 16-lane group. 8 phases, one src-octant each:
//   - soft barrier (bounded spin, locality-only -> deadlock-free),
//   - sequential prefetch: 128 blocks sharing blockIdx&7 (same XCD under
//     round-robin dispatch) stream the 3.2 MB slice into their L2 (one 4 B
//     touch per 64 B line), converting the compulsory per-XCD replication
//     traffic from random-latency-bound (~2.4 TB/s) to streaming (~6 TB/s),
//   - gather: demand loads hit L2 or merge with in-flight fills.
__global__ __launch_bounds__(256, 4) void k_aggp(
    const float* __restrict__ H, const float* __restrict__ als,
    const float* __restrict__ ald, const int* __restrict__ starts,
    const int* __restrict__ cnts, const int* __restrict__ col,
    const float* __restrict__ bias, const int* __restrict__ batch,
    const float* __restrict__ hw, float* __restrict__ out,
    float* __restrict__ Hout, int* __restrict__ ctr, int last) {
    int tid = threadIdx.x;
    int b = blockIdx.x;
    int g = tid >> 4;
    int l = tid & 15;
    int hsel = l >> 2;
    int gid = b * 16 + g;
    int rid = b >> 3;   // rank among the 128 blocks on this XCD (b&7 == XCD heuristic)
    const float4* Hp = (const float4*)H + l;

    float4 acc[NSLOT];
    float ssum[NSLOT];
    float adh[NSLOT];
#pragma unroll
    for (int t = 0; t < NSLOT; t++) {
        acc[t] = make_float4(0.f, 0.f, 0.f, 0.f);
        ssum[t] = 0.f;
        int n = gid + t * NGRP;
        adh[t] = (n < NN) ? ald[(size_t)n * 4 + hsel] : 0.f;
    }

    for (int p = 0; p < NOCT; p++) {
        // soft barrier: align all blocks on octant p (bounded spin, never blocks)
        __syncthreads();
        if (tid == 0) {
            __hip_atomic_fetch_add(&ctr[p], 1, __ATOMIC_RELAXED, __HIP_MEMORY_SCOPE_AGENT);
            int polls = 0;
            while (polls++ < 64 &&
                   __hip_atomic_load(&ctr[p], __ATOMIC_RELAXED, __HIP_MEMORY_SCOPE_AGENT) < NBLK_AGG)
                __builtin_amdgcn_s_sleep(1);
        }
        __syncthreads();

        // sequential slice prefetch into this XCD's L2 (4 B per 64 B line)
        {
            const char* sb = (const char*)H + (size_t)p * SLICE_BYTES + (size_t)rid * PFCHUNK;
            int o0 = tid * 64;
            int o1 = 16384 + tid * 64;
            float pf0 = (o0 < PFCHUNK) ? *(const float*)(sb + o0) : 0.f;
            float pf1 = (o1 < PFCHUNK) ? *(const float*)(sb + o1) : 0.f;
            asm volatile("" :: "v"(pf0), "v"(pf1));
        }

        // gather this octant's edges for each owned node (2 edges in flight)
#pragma unroll
        for (int t = 0; t < NSLOT; t++) {
            int n = gid + t * NGRP;
            if (n < NN) {
                int sidx = n * 8 + p;
                int st = starts[sidx];
                int c  = cnts[sidx];
                int e = st, end = st + c;
                float ad = adh[t];
                for (; e + 2 <= end; e += 2) {
                    int s0 = col[e], s1 = col[e + 1];
                    float a0 = als[(size_t)s0 * 4 + hsel];
                    float a1 = als[(size_t)s1 * 4 + hsel];
                    float4 h0 = Hp[(size_t)s0 * 16];
                    float4 h1 = Hp[(size_t)s1 * 16];
                    float w0 = __expf(lrelu(a0 + ad));
                    float w1 = __expf(lrelu(a1 + ad));
                    ssum[t] += w0 + w1;
                    acc[t].x = fmaf(w0, h0.x, fmaf(w1, h1.x, acc[t].x));
                    acc[t].y = fmaf(w0, h0.y, fmaf(w1, h1.y, acc[t].y));
                    acc[t].z = fmaf(w0, h0.z, fmaf(w1, h1.z, acc[t].z));
                    acc[t].w = fmaf(w0, h0.w, fmaf(w1, h1.w, acc[t].w));
                }
                if (e < end) {
                    int s0 = col[e];
                    float a0 = als[(size_t)s0 * 4 + hsel];
                    float4 h0 = Hp[(size_t)s0 * 16];
                    float w0 = __expf(lrelu(a0 + ad));
                    ssum[t] += w0;
                    acc[t].x = fmaf(w0, h0.x, acc[t].x);
                    acc[t].y = fmaf(w0, h0.y, acc[t].y);
                    acc[t].z = fmaf(w0, h0.z, acc[t].z);
                    acc[t].w = fmaf(w0, h0.w, acc[t].w);
                }
            }
        }
    }

    // finalize: normalize + bias + relu, then either store rows or head+pool
    float4 b4 = ((const float4*)bias)[l];
    float4 w4 = make_float4(0.f, 0.f, 0.f, 0.f);
    if (last) w4 = ((const float4*)hw)[l];
#pragma unroll
    for (int t = 0; t < NSLOT; t++) {
        int n = gid + t * NGRP;
        if (n < NN) {
            float inv = 1.f / (ssum[t] + 1e-16f);
            float4 o;
            o.x = fmaxf(acc[t].x * inv + b4.x, 0.f);
            o.y = fmaxf(acc[t].y * inv + b4.y, 0.f);
            o.z = fmaxf(acc[t].z * inv + b4.z, 0.f);
            o.w = fmaxf(acc[t].w * inv + b4.w, 0.f);
            if (!last) {
                ((float4*)Hout)[(size_t)n * 16 + l] = o;
            } else {
                float tt = o.x * w4.x + o.y * w4.y + o.z * w4.z + o.w * w4.w;
#pragma unroll
                for (int off = 8; off > 0; off >>= 1) tt += __shfl_xor(tt, off, 16);
                if (l == 0) atomicAdd(&out[batch[n]], tt);
            }
        }
    }
}

// ---------------- launch -----------------------------------------------------
extern "C" void kernel_launch(void* const* d_in, const int* in_sizes, int n_in,
                              void* d_out, int out_size, void* d_ws, size_t ws_size,
                              hipStream_t stream) {
    const float* x     = (const float*)d_in[0];
    const int*   ei    = (const int*)d_in[1];
    const int*   batch = (const int*)d_in[2];
    const float* Wm[3] = {(const float*)d_in[3], (const float*)d_in[7],  (const float*)d_in[11]};
    const float* As[3] = {(const float*)d_in[4], (const float*)d_in[8],  (const float*)d_in[12]};
    const float* Ad[3] = {(const float*)d_in[5], (const float*)d_in[9],  (const float*)d_in[13]};
    const float* Bb[3] = {(const float*)d_in[6], (const float*)d_in[10], (const float*)d_in[14]};
    const float* hw = (const float*)d_in[15];
    const float* hb = (const float*)d_in[16];
    float* out = (float*)d_out;

    uint8_t* w = (uint8_t*)d_ws;
    auto alloc = [&](size_t bytes) -> void* {
        void* p = (void*)w;
        w += (bytes + 255) & ~(size_t)255;
        return p;
    };
    float* H     = (float*)alloc((size_t)NN * 64 * 4);   // ping (gather source)
    float* Bf    = (float*)alloc((size_t)NN * 64 * 4);   // pong
    float* als   = (float*)alloc((size_t)NN * 4 * 4);
    float* ald   = (float*)alloc((size_t)NN * 4 * 4);
    int*   meta  = (int*)alloc(((size_t)NN * 8 + 64) * 4);  // deg2 + cursor + ctr
    int*   starts= (int*)alloc((size_t)NN * 8 * 4);
    int*   rank2 = (int*)alloc((size_t)(EE + NN) * 4);
    int*   col   = (int*)alloc((size_t)(EE + NN) * 4);

    int* deg2   = meta;
    int* cursor = meta + (size_t)NN * 8;
    int* ctr    = cursor + 8;          // 24 phase counters (3 layers x 8)

    hipMemsetAsync(meta, 0, ((size_t)NN * 8 + 64) * 4, stream);

    int eb = (EE + NN + 255) / 256;
    // histogram (dst,octant) || layer-0 GEMM in one grid
    k_cg<<<NB_CNT + NB_GEMM, 256, 0, stream>>>(ei, deg2, rank2,
                                               x, Wm[0], As[0], Ad[0], H, als, ald);
    k_alloc2<<<(NN + 255) / 256, 256, 0, stream>>>(deg2, starts, cursor, hb, out);
    k_scatter2<<<eb, 256, 0, stream>>>(ei, starts, rank2, col);

    // layer 0
    k_aggp<<<NBLK_AGG, 256, 0, stream>>>(H, als, ald, starts, deg2, col, Bb[0],
                                         batch, hw, out, Bf, ctr + 0, 0);
    // layer 1
    k_gemm<64><<<NB_GEMM, 256, 0, stream>>>(Bf, Wm[1], As[1], Ad[1], H, als, ald);
    k_aggp<<<NBLK_AGG, 256, 0, stream>>>(H, als, ald, starts, deg2, col, Bb[1],
                                         batch, hw, out, Bf, ctr + 8, 0);
    // layer 2
    k_gemm<64><<<NB_GEMM, 256, 0, stream>>>(Bf, Wm[2], As[2], Ad[2], H, als, ald);
    k_aggp<<<NBLK_AGG, 256, 0, stream>>>(H, als, ald, starts, deg2, col, Bb[2],
                                         batch, hw, out, H /*unused*/, ctr + 16, 1);
}

// Round 4
// 539.466 us; speedup vs baseline: 3.4247x; 3.4247x over previous
//
#include <hip/hip_runtime.h>
#include <hip/hip_bf16.h>
#include <hip/hip_fp16.h>
#include <cstdint>
#include <cstddef>

#define NN 100000
#define EE 1600000
#define GG 2048

#define NOCT 8
#define OCTW 12500    // NN / NOCT: src rows per octant

constexpr int NB_CNT  = (EE + NN + 255) / 256;  // 6641 count blocks
constexpr int NB_GEMM = NN / 16;                // 6250 gemm blocks

__device__ __forceinline__ float lrelu(float v) { return v > 0.f ? v : 0.2f * v; }

// ---------------- shared GEMM body (layer GEMM + attention-logit epilogue) --
// One wave = 4 rows; x-row pointers wave-uniform (SGPR via readfirstlane).
template <int FIN>
__device__ __forceinline__ void gemm_body(int bidx, const float* __restrict__ X,
                                          const float* __restrict__ W,
                                          const float* __restrict__ asrc,
                                          const float* __restrict__ adst,
                                          float* __restrict__ H,
                                          float* __restrict__ als,
                                          float* __restrict__ ald) {
    int j  = threadIdx.x & 63;
    int ty = threadIdx.x >> 6;
    int row = __builtin_amdgcn_readfirstlane(bidx * 16 + ty * 4);
    const float* x0 = X + (size_t)row * FIN;
    const float* x1 = x0 + FIN;
    const float* x2 = x1 + FIN;
    const float* x3 = x2 + FIN;
    float a0 = 0.f, a1 = 0.f, a2 = 0.f, a3 = 0.f;
#pragma unroll
    for (int k = 0; k < FIN; k += 4) {
        float4 xa = *(const float4*)(x0 + k);
        float4 xb = *(const float4*)(x1 + k);
        float4 xc = *(const float4*)(x2 + k);
        float4 xd = *(const float4*)(x3 + k);
        float w0 = W[(k + 0) * 64 + j];
        float w1 = W[(k + 1) * 64 + j];
        float w2 = W[(k + 2) * 64 + j];
        float w3 = W[(k + 3) * 64 + j];
        a0 += xa.x * w0 + xa.y * w1 + xa.z * w2 + xa.w * w3;
        a1 += xb.x * w0 + xb.y * w1 + xb.z * w2 + xb.w * w3;
        a2 += xc.x * w0 + xc.y * w1 + xc.z * w2 + xc.w * w3;
        a3 += xd.x * w0 + xd.y * w1 + xd.z * w2 + xd.w * w3;
    }
    H[(size_t)(row + 0) * 64 + j] = a0;
    H[(size_t)(row + 1) * 64 + j] = a1;
    H[(size_t)(row + 2) * 64 + j] = a2;
    H[(size_t)(row + 3) * 64 + j] = a3;
    float asj = asrc[j], adj = adst[j];
    float accs[4] = {a0, a1, a2, a3};
#pragma unroll
    for (int r = 0; r < 4; r++) {
        float vs = accs[r] * asj;
        float vd = accs[r] * adj;
#pragma unroll
        for (int off = 8; off > 0; off >>= 1) {
            vs += __shfl_xor(vs, off, 64);
            vd += __shfl_xor(vd, off, 64);
        }
        if ((j & 15) == 0) {
            int h = j >> 4;
            als[(size_t)(row + r) * 4 + h] = vs;
            ald[(size_t)(row + r) * 4 + h] = vd;
        }
    }
}

template <int FIN>
__global__ __launch_bounds__(256) void k_gemm(const float* __restrict__ X,
                                              const float* __restrict__ W,
                                              const float* __restrict__ asrc,
                                              const float* __restrict__ adst,
                                              float* __restrict__ H,
                                              float* __restrict__ als,
                                              float* __restrict__ ald) {
    gemm_body<FIN>(blockIdx.x, X, W, asrc, adst, H, als, ald);
}

// ---------------- fused (dst,src-octant) histogram + layer-0 GEMM -----------
// Independent work, complementary pipes: counting is atomic/fabric-bound, the
// GEMM is VALU/stream-bound. Fusing them in one grid hides the cheaper one.
__global__ __launch_bounds__(256) void k_cg(const int* __restrict__ ei,
                                            int* __restrict__ deg2,
                                            int* __restrict__ rank2,
                                            const float* __restrict__ X,
                                            const float* __restrict__ W,
                                            const float* __restrict__ asrc,
                                            const float* __restrict__ adst,
                                            float* __restrict__ H,
                                            float* __restrict__ als,
                                            float* __restrict__ ald) {
    if (blockIdx.x < NB_CNT) {
        int i = blockIdx.x * 256 + threadIdx.x;
        if (i < EE + NN) {
            int s, d;
            if (i < EE) { s = ei[i]; d = ei[EE + i]; } else { s = d = i - EE; }
            unsigned oct = (unsigned)s / OCTW;
            rank2[i] = atomicAdd(&deg2[d * 8 + oct], 1);
        }
    } else {
        gemm_body<128>(blockIdx.x - NB_CNT, X, W, asrc, adst, H, als, ald);
    }
}

// ---------------- per-(dst,octant) segment offsets (unordered alloc) --------
// Node n gets a contiguous [offs[n], offs[n]+deg[n]) range with octant
// sub-segments in ascending order -> col ends up bucket-sorted by src-octant
// within every dst segment. Gather kernels consume plain offs/deg (identical
// interface to the round-2 structure). out[] init folded in.
__global__ void k_alloc2(const int* __restrict__ deg2, int* __restrict__ starts,
                         int* __restrict__ offs, int* __restrict__ deg,
                         int* __restrict__ cursor, const float* __restrict__ head_b,
                         float* __restrict__ out) {
    int i = blockIdx.x * 256 + threadIdx.x;
    int lane = threadIdx.x & 63;
    int rel[8];
    int tot = 0;
    if (i < NN) {
#pragma unroll
        for (int o = 0; o < 8; o++) { rel[o] = tot; tot += deg2[i * 8 + o]; }
    }
    int incl = tot;
#pragma unroll
    for (int off = 1; off < 64; off <<= 1) {
        int t = __shfl_up(incl, off, 64);
        if (lane >= off) incl += t;
    }
    int wtot = __shfl(incl, 63, 64);
    int base = 0;
    if (lane == 63) base = atomicAdd(cursor, wtot);
    base = __shfl(base, 63, 64);
    int mybase = base + incl - tot;
    if (i < NN) {
#pragma unroll
        for (int o = 0; o < 8; o++) starts[i * 8 + o] = mybase + rel[o];
        offs[i] = mybase;
        deg[i]  = tot;
    }
    if (i < GG) out[i] = head_b[0];
}

__global__ void k_scatter2(const int* __restrict__ ei, const int* __restrict__ starts,
                           const int* __restrict__ rank2, int* __restrict__ col) {
    int i = blockIdx.x * blockDim.x + threadIdx.x;
    if (i >= EE + NN) return;
    int s, d;
    if (i < EE) { s = ei[i]; d = ei[EE + i]; } else { s = d = i - EE; }
    unsigned oct = (unsigned)s / OCTW;
    col[starts[d * 8 + oct] + rank2[i]] = s;
}

// ---------------- fused aggregate(L) + GEMM(L+1) ----------------------------
// Round-2 structure verbatim (8 edges in flight, no-max softmax, fused next-
// layer GEMM from LDS). Only the data changed: col is octant-sorted per dst,
// so concurrent groups sweep src-space 0->7 together and the instantaneous
// hot window of H (~2.5 octants ~ 8 MB) mostly fits the per-XCD L2.
__global__ __launch_bounds__(256) void k_aggf(
    const float* __restrict__ H, const float* __restrict__ als,
    const float* __restrict__ ald, const int* __restrict__ offs,
    const int* __restrict__ deg, const int* __restrict__ col,
    const float* __restrict__ bias,          // layer L bias (on aggregated out)
    const float* __restrict__ W,             // layer L+1 weights [64][64]
    const float* __restrict__ asrc,          // layer L+1 a_src [4][16]
    const float* __restrict__ adst,          // layer L+1 a_dst [4][16]
    float* __restrict__ Hn, float* __restrict__ alsn, float* __restrict__ aldn) {
    __shared__ float wl[4096];       // W staged: 16 KB
    __shared__ float xs[16 * 68];    // 16 rows, stride 68 (bank-conflict pad)
    int tid = threadIdx.x;
    int g = tid >> 4;          // group (node) 0..15
    int l = tid & 15;          // lane in group = float4-chunk index 0..15
    int n = blockIdx.x * 16 + g;   // NN % 16 == 0 -> always valid
    int start = offs[n];
    int len = deg[n];
    int hsel = l >> 2;         // head of this lane's channel quad
    float adh = ald[(size_t)n * 4 + hsel];
    const float4* Hp = (const float4*)H + l;

    // stage W while the gather waits on memory
#pragma unroll
    for (int t = 0; t < 4; t++)
        ((float4*)wl)[tid + t * 256] = ((const float4*)W)[tid + t * 256];

    float4 acc = {0.f, 0.f, 0.f, 0.f};
    float ssum = 0.f;
    for (int e = 0; e < len; e += 8) {
        bool  v[8];
        int   s[8];
#pragma unroll
        for (int i = 0; i < 8; i++) {
            v[i] = (e + i < len);
            s[i] = v[i] ? col[start + e + i] : 0;
        }
        float  w[8];
        float4 hr[8];
#pragma unroll
        for (int i = 0; i < 8; i++) {
            float a = als[(size_t)s[i] * 4 + hsel];
            hr[i] = Hp[(size_t)s[i] * 16];
            float ev = lrelu(a + adh);
            w[i] = v[i] ? __expf(ev) : 0.f;
        }
#pragma unroll
        for (int i = 0; i < 8; i++) {
            ssum  += w[i];
            acc.x = fmaf(w[i], hr[i].x, acc.x);
            acc.y = fmaf(w[i], hr[i].y, acc.y);
            acc.z = fmaf(w[i], hr[i].z, acc.z);
            acc.w = fmaf(w[i], hr[i].w, acc.w);
        }
    }
    float inv = 1.f / (ssum + 1e-16f);
    float4 b4 = ((const float4*)bias)[l];
    float* xr = xs + g * 68 + 4 * l;
    xr[0] = fmaxf(acc.x * inv + b4.x, 0.f);
    xr[1] = fmaxf(acc.y * inv + b4.y, 0.f);
    xr[2] = fmaxf(acc.z * inv + b4.z, 0.f);
    xr[3] = fmaxf(acc.w * inv + b4.w, 0.f);

    __syncthreads();   // xs + wl ready

    // ---- GEMM: thread (g,l) -> row n, output channels 4l..4l+3 ------------
    float4 o = {0.f, 0.f, 0.f, 0.f};
    const float* xrow = xs + g * 68;
    const float* wcol = wl + 4 * l;
#pragma unroll
    for (int k = 0; k < 64; k += 4) {
        float4 xv = *(const float4*)(xrow + k);
        float4 w0 = *(const float4*)(wcol + (k + 0) * 64);
        float4 w1 = *(const float4*)(wcol + (k + 1) * 64);
        float4 w2 = *(const float4*)(wcol + (k + 2) * 64);
        float4 w3 = *(const float4*)(wcol + (k + 3) * 64);
        o.x += xv.x * w0.x + xv.y * w1.x + xv.z * w2.x + xv.w * w3.x;
        o.y += xv.x * w0.y + xv.y * w1.y + xv.z * w2.y + xv.w * w3.y;
        o.z += xv.x * w0.z + xv.y * w1.z + xv.z * w2.z + xv.w * w3.z;
        o.w += xv.x * w0.w + xv.y * w1.w + xv.z * w2.w + xv.w * w3.w;
    }
    ((float4*)Hn)[(size_t)n * 16 + l] = o;

    // attention logits for layer L+1: channels 4l..4l+3 are all in head l>>2
    float4 av = ((const float4*)asrc)[l];
    float4 dv = ((const float4*)adst)[l];
    float vs = o.x * av.x + o.y * av.y + o.z * av.z + o.w * av.w;
    float vd = o.x * dv.x + o.y * dv.y + o.z * dv.z + o.w * dv.w;
    vs += __shfl_xor(vs, 1, 16); vs += __shfl_xor(vs, 2, 16);
    vd += __shfl_xor(vd, 1, 16); vd += __shfl_xor(vd, 2, 16);
    if ((l & 3) == 0) {
        int h = l >> 2;
        alsn[(size_t)n * 4 + h] = vs;
        aldn[(size_t)n * 4 + h] = vd;
    }
}

// ---------------- last layer: aggregate + head projection + pool ------------
__global__ __launch_bounds__(256) void k_aggl(
    const float* __restrict__ H, const float* __restrict__ als,
    const float* __restrict__ ald, const int* __restrict__ offs,
    const int* __restrict__ deg, const int* __restrict__ col,
    const float* __restrict__ bias, const int* __restrict__ batch,
    const float* __restrict__ hw, float* __restrict__ out) {
    int tid = threadIdx.x;
    int g = tid >> 4;
    int l = tid & 15;
    int n = blockIdx.x * 16 + g;
    int start = offs[n];
    int len = deg[n];
    int hsel = l >> 2;
    float adh = ald[(size_t)n * 4 + hsel];
    const float4* Hp = (const float4*)H + l;

    float4 acc = {0.f, 0.f, 0.f, 0.f};
    float ssum = 0.f;
    for (int e = 0; e < len; e += 8) {
        bool  v[8];
        int   s[8];
#pragma unroll
        for (int i = 0; i < 8; i++) {
            v[i] = (e + i < len);
            s[i] = v[i] ? col[start + e + i] : 0;
        }
        float  w[8];
        float4 hr[8];
#pragma unroll
        for (int i = 0; i < 8; i++) {
            float a = als[(size_t)s[i] * 4 + hsel];
            hr[i] = Hp[(size_t)s[i] * 16];
            float ev = lrelu(a + adh);
            w[i] = v[i] ? __expf(ev) : 0.f;
        }
#pragma unroll
        for (int i = 0; i < 8; i++) {
            ssum  += w[i];
            acc.x = fmaf(w[i], hr[i].x, acc.x);
            acc.y = fmaf(w[i], hr[i].y, acc.y);
            acc.z = fmaf(w[i], hr[i].z, acc.z);
            acc.w = fmaf(w[i], hr[i].w, acc.w);
        }
    }
    float inv = 1.f / (ssum + 1e-16f);
    float4 b4 = ((const float4*)bias)[l];
    float4 w4 = ((const float4*)hw)[l];
    float t = fmaxf(acc.x * inv + b4.x, 0.f) * w4.x
            + fmaxf(acc.y * inv + b4.y, 0.f) * w4.y
            + fmaxf(acc.z * inv + b4.z, 0.f) * w4.z
            + fmaxf(acc.w * inv + b4.w, 0.f) * w4.w;
#pragma unroll
    for (int off = 8; off > 0; off >>= 1) t += __shfl_xor(t, off, 16);
    if (l == 0) atomicAdd(&out[batch[n]], t);
}

// ---------------- launch -----------------------------------------------------
extern "C" void kernel_launch(void* const* d_in, const int* in_sizes, int n_in,
                              void* d_out, int out_size, void* d_ws, size_t ws_size,
                              hipStream_t stream) {
    const float* x     = (const float*)d_in[0];
    const int*   ei    = (const int*)d_in[1];
    const int*   batch = (const int*)d_in[2];
    const float* Wm[3] = {(const float*)d_in[3], (const float*)d_in[7],  (const float*)d_in[11]};
    const float* As[3] = {(const float*)d_in[4], (const float*)d_in[8],  (const float*)d_in[12]};
    const float* Ad[3] = {(const float*)d_in[5], (const float*)d_in[9],  (const float*)d_in[13]};
    const float* Bb[3] = {(const float*)d_in[6], (const float*)d_in[10], (const float*)d_in[14]};
    const float* hw = (const float*)d_in[15];
    const float* hb = (const float*)d_in[16];
    float* out = (float*)d_out;

    uint8_t* w = (uint8_t*)d_ws;
    auto alloc = [&](size_t bytes) -> void* {
        void* p = (void*)w;
        w += (bytes + 255) & ~(size_t)255;
        return p;
    };
    float* H      = (float*)alloc((size_t)NN * 64 * 4);   // ping (gather source)
    float* Bf     = (float*)alloc((size_t)NN * 64 * 4);   // pong
    float* als    = (float*)alloc((size_t)NN * 4 * 4);
    float* ald    = (float*)alloc((size_t)NN * 4 * 4);
    float* als2   = (float*)alloc((size_t)NN * 4 * 4);
    float* ald2   = (float*)alloc((size_t)NN * 4 * 4);
    int*   meta   = (int*)alloc(((size_t)NN * 8 + 64) * 4);  // deg2 + cursor
    int*   starts = (int*)alloc((size_t)NN * 8 * 4);
    int*   offs   = (int*)alloc((size_t)NN * 4);
    int*   deg    = (int*)alloc((size_t)NN * 4);
    int*   rank2  = (int*)alloc((size_t)(EE + NN) * 4);
    int*   col    = (int*)alloc((size_t)(EE + NN) * 4);

    int* deg2   = meta;
    int* cursor = meta + (size_t)NN * 8;

    hipMemsetAsync(meta, 0, ((size_t)NN * 8 + 64) * 4, stream);

    int eb = (EE + NN + 255) / 256;
    // (dst, src-octant) histogram || layer-0 GEMM in one grid
    k_cg<<<NB_CNT + NB_GEMM, 256, 0, stream>>>(ei, deg2, rank2,
                                               x, Wm[0], As[0], Ad[0], H, als, ald);
    k_alloc2<<<(NN + 255) / 256, 256, 0, stream>>>(deg2, starts, offs, deg,
                                                   cursor, hb, out);
    k_scatter2<<<eb, 256, 0, stream>>>(ei, starts, rank2, col);

    k_aggf<<<NN / 16, 256, 0, stream>>>(H,  als,  ald,  offs, deg, col, Bb[0],
                                        Wm[1], As[1], Ad[1], Bf, als2, ald2);
    k_aggf<<<NN / 16, 256, 0, stream>>>(Bf, als2, ald2, offs, deg, col, Bb[1],
                                        Wm[2], As[2], Ad[2], H, als, ald);
    k_aggl<<<NN / 16, 256, 0, stream>>>(H,  als,  ald,  offs, deg, col, Bb[2],
                                        batch, hw, out);
}